// Round 12
// baseline (122.704 us; speedup 1.0000x reference)
//
#include <hip/hip_runtime.h>
#include <hip/hip_bf16.h>
#include <math.h>

// ---------------------------------------------------------------------------
// Math note: softmax(A, axis=2) then sum(A, axis=2, keepdims=True) * V == V.
// Pipeline: X1 = LN(X + X@Wv + bv); out = LN(X1 + relu(X1@W1+b1)@W2 + b2)
//
// Round-12 = round-11 (120.9us) + GEMM1 reads X directly in fp32
// (reg-staged cvt + ds_write into the same swizzled layout) -> the 6us
// X-cast pass in prep is deleted. GEMM2/GEMM3/LNs/transposes unchanged.
//  - GEMM1 (8192x768x768):  gemm1_f32a, grid 512 (fp32 A, Wv+I folded)
//  - GEMM2 (8192x3072x768): gemm128<192,2>, grid 1024
//  - GEMM3 (8192x768x3072): gemm128<96,3>, grid 512
// ---------------------------------------------------------------------------

typedef __bf16 bf16x8 __attribute__((ext_vector_type(8)));
typedef float f32x4 __attribute__((ext_vector_type(4)));

__device__ inline void gload_lds16(const __hip_bfloat16* g, void* lds) {
  __builtin_amdgcn_global_load_lds(
      (const __attribute__((address_space(1))) void*)g,
      (__attribute__((address_space(3))) void*)lds, 16, 0, 0);
}

__device__ inline float bf2f(unsigned short u) {
  union { unsigned int i; float f; } x;
  x.i = ((unsigned int)u) << 16;
  return x.f;
}

#define BARRIER() asm volatile("s_barrier" ::: "memory")

template <int N>
__device__ __forceinline__ void vmwait() {
  if constexpr (N == 0)
    asm volatile("s_waitcnt vmcnt(0)" ::: "memory");
  else if constexpr (N == 3)
    asm volatile("s_waitcnt vmcnt(3)" ::: "memory");
  else if constexpr (N == 7)
    asm volatile("s_waitcnt vmcnt(7)" ::: "memory");
  else if constexpr (N == 8)
    asm volatile("s_waitcnt vmcnt(8)" ::: "memory");
  else if constexpr (N == 10)
    asm volatile("s_waitcnt vmcnt(10)" ::: "memory");
  else if constexpr (N == 11)
    asm volatile("s_waitcnt vmcnt(11)" ::: "memory");
}

template <int N>
__device__ __forceinline__ void lgwait() {
  if constexpr (N == 0)
    asm volatile("s_waitcnt lgkmcnt(0)" ::: "memory");
  else if constexpr (N == 7)
    asm volatile("s_waitcnt lgkmcnt(7)" ::: "memory");
  else if constexpr (N == 8)
    asm volatile("s_waitcnt lgkmcnt(8)" ::: "memory");
  else if constexpr (N == 10)
    asm volatile("s_waitcnt lgkmcnt(10)" ::: "memory");
}

// ==================== gemm128 (proven; GEMM2/GEMM3) ========================
// C(MxN) = A(MxK) @ Bt(NxK)^T, 128 x BNv tile, BK=64, 4 waves (2x2).
// EPI==2: +bias relu; EPI==3: +bias +bf16 residual; EPI==4: +bias only.
template <int BNv, int EPI>
__global__ __launch_bounds__(256, 2) void gemm128(
    const __hip_bfloat16* __restrict__ A, const __hip_bfloat16* __restrict__ Bt,
    __hip_bfloat16* __restrict__ C, const float* __restrict__ bias,
    const __hip_bfloat16* __restrict__ residb, int M, int N, int K) {
  constexpr int NF = BNv / 32;
  constexpr int BI = BNv / 32;
  constexpr int BS = BNv * 128;
  constexpr int S = 4 + BI;
  __shared__ __align__(16) char smem[32768 + 2 * BS];

  const int bid = blockIdx.x;
  const int mB = M / 128;
  const int rowBase = (bid % mB) * 128;
  const int colBase = (bid / mB) * BNv;
  const int nt = K / 64;

  const int wv = threadIdx.x >> 6;
  const int lane = threadIdx.x & 63;
  const int wr = wv >> 1, wc = wv & 1;
  const int l16 = lane & 15, lk = lane >> 4;

  const int rA = lane >> 3;
  const int cSw = ((lane & 7) ^ rA) * 8;
  const __hip_bfloat16* gA = A + (size_t)(rowBase + wv * 32 + rA) * K + cSw;
  const __hip_bfloat16* gB =
      Bt + (size_t)(colBase + wv * 8 * BI + rA) * K + cSw;

  auto STAGE = [&](int kt, int b) {
    const size_t ko = (size_t)kt * 64;
#pragma unroll
    for (int i = 0; i < 4; ++i)
      gload_lds16(gA + (size_t)i * 8 * K + ko,
                  smem + b * 16384 + (wv * 4 + i) * 1024);
#pragma unroll
    for (int i = 0; i < BI; ++i)
      gload_lds16(gB + (size_t)i * 8 * K + ko,
                  smem + 32768 + b * BS + (wv * BI + i) * 1024);
  };

  const int aBase = (wr * 64 + l16) * 128;
  const int bBase = (wc * (BNv / 2) + l16) * 128;
  const int xr = l16 & 7;
  const int cph0 = ((lk) ^ xr) * 16;
  const int cph1 = ((4 + lk) ^ xr) * 16;

  f32x4 acc[4][NF];
#pragma unroll
  for (int m = 0; m < 4; ++m)
#pragma unroll
    for (int n = 0; n < NF; ++n) acc[m][n] = (f32x4){0.f, 0.f, 0.f, 0.f};

  STAGE(0, 0);
  if (nt > 1) {
    STAGE(1, 1);
    vmwait<S>();
  } else {
    vmwait<0>();
  }
  BARRIER();

  for (int t = 0; t < nt; ++t) {
    const int b = t & 1;
    const char* pa = smem + b * 16384 + aBase;
    const char* pb = smem + 32768 + b * BS + bBase;

    bf16x8 af0[4], af1[4], bf0[NF], bf1[NF];
#pragma unroll
    for (int m = 0; m < 4; ++m) af0[m] = *(const bf16x8*)(pa + m * 2048 + cph0);
#pragma unroll
    for (int n = 0; n < NF; ++n) bf0[n] = *(const bf16x8*)(pb + n * 2048 + cph0);
#pragma unroll
    for (int m = 0; m < 4; ++m) af1[m] = *(const bf16x8*)(pa + m * 2048 + cph1);
#pragma unroll
    for (int n = 0; n < NF; ++n) bf1[n] = *(const bf16x8*)(pb + n * 2048 + cph1);

    lgwait<S>();
    __builtin_amdgcn_sched_barrier(0);
    __builtin_amdgcn_s_setprio(1);
#pragma unroll
    for (int m = 0; m < 4; ++m)
#pragma unroll
      for (int n = 0; n < NF; ++n)
        acc[m][n] = __builtin_amdgcn_mfma_f32_16x16x32_bf16(af0[m], bf0[n],
                                                            acc[m][n], 0, 0, 0);
    __builtin_amdgcn_s_setprio(0);
    lgwait<0>();
    __builtin_amdgcn_sched_barrier(0);
    BARRIER();

    if (t + 2 < nt) STAGE(t + 2, b);

    __builtin_amdgcn_s_setprio(1);
#pragma unroll
    for (int m = 0; m < 4; ++m)
#pragma unroll
      for (int n = 0; n < NF; ++n)
        acc[m][n] = __builtin_amdgcn_mfma_f32_16x16x32_bf16(af1[m], bf1[n],
                                                            acc[m][n], 0, 0, 0);
    __builtin_amdgcn_s_setprio(0);

    if (t + 1 < nt) {
      if (t + 2 < nt)
        vmwait<S>();
      else
        vmwait<0>();
      BARRIER();
    }
  }

#pragma unroll
  for (int m = 0; m < 4; ++m) {
#pragma unroll
    for (int n = 0; n < NF; ++n) {
#pragma unroll
      for (int j = 0; j < 4; ++j) {
        const int r = rowBase + wr * 64 + m * 16 + lk * 4 + j;
        const int c = colBase + wc * (BNv / 2) + n * 16 + l16;
        const size_t idx = (size_t)r * N + c;
        float v = acc[m][n][j] + bias[c];
        if (EPI == 2) v = fmaxf(v, 0.f);
        if (EPI == 3) v += __bfloat162float(residb[idx]);
        C[idx] = __float2bfloat16(v);
      }
    }
  }
}

// ============== gemm1_f32a: GEMM1 with fp32 A (reg-staged cvt) ==============
// C = A(MxK fp32) @ Bt(NxK bf16)^T + bias.  128x96 tile, BK=64, 4 waves.
__global__ __launch_bounds__(256, 2) void gemm1_f32a(
    const float* __restrict__ A, const __hip_bfloat16* __restrict__ Bt,
    __hip_bfloat16* __restrict__ C, const float* __restrict__ bias,
    int M, int N, int K) {
  // smem: A0[16K] A1[16K] B0[12K] B1[12K]
  __shared__ __align__(16) char smem[32768 + 2 * 12288];
  const int bid = blockIdx.x;
  const int mB = M / 128;
  const int rowBase = (bid % mB) * 128;
  const int colBase = (bid / mB) * 96;
  const int nt = K / 64;

  const int wv = threadIdx.x >> 6;
  const int lane = threadIdx.x & 63;
  const int wr = wv >> 1, wc = wv & 1;
  const int l16 = lane & 15, lk = lane >> 4;

  // B staging (bf16, gload_lds; 3 loads/wave covers 96 rows)
  const int rB = lane >> 3;
  const int cSwB = ((lane & 7) ^ rB) * 8;
  const __hip_bfloat16* gB = Bt + (size_t)(colBase + wv * 24 + rB) * K + cSwB;

  // A staging (fp32 -> regs -> cvt -> swizzled ds_write_b64)
  // load i covers rows wv*32 + i*4 + (lane>>4); lane covers floats
  // (lane&15)*4 .. +3 of that row.
  const float* gA =
      A + (size_t)(rowBase + wv * 32 + (lane >> 4)) * K + (lane & 15) * 4;
  float4 ar[8];

  auto ISSUE = [&](int kt, int b) {
#pragma unroll
    for (int i = 0; i < 8; ++i)
      ar[i] = *reinterpret_cast<const float4*>(gA + (size_t)(i * 4) * K +
                                               (size_t)kt * 64);
#pragma unroll
    for (int i = 0; i < 3; ++i)
      gload_lds16(gB + (size_t)i * 8 * K + (size_t)kt * 64,
                  smem + 32768 + b * 12288 + (wv * 3 + i) * 1024);
  };

  // write A regs (already loaded) to buffer b in swizzled layout:
  // row r, logical chunk c=(lane&15)>>1 stored at phys chunk c^(r&7),
  // half (lane&1)*8 bytes.
  auto WRITEA = [&](int b) {
#pragma unroll
    for (int i = 0; i < 8; ++i) {
      const int rit = wv * 32 + i * 4 + (lane >> 4);
      const int p = ((lane & 15) >> 1) ^ (rit & 7);
      char* dst = smem + b * 16384 + rit * 128 + p * 16 + (lane & 1) * 8;
      __hip_bfloat16 h0 = __float2bfloat16(ar[i].x);
      __hip_bfloat16 h1 = __float2bfloat16(ar[i].y);
      __hip_bfloat16 h2 = __float2bfloat16(ar[i].z);
      __hip_bfloat16 h3 = __float2bfloat16(ar[i].w);
      ushort4 o;
      o.x = *reinterpret_cast<unsigned short*>(&h0);
      o.y = *reinterpret_cast<unsigned short*>(&h1);
      o.z = *reinterpret_cast<unsigned short*>(&h2);
      o.w = *reinterpret_cast<unsigned short*>(&h3);
      *reinterpret_cast<ushort4*>(dst) = o;
    }
  };

  // ds_read addressing (identical to gemm128<96>)
  const int aBase = (wr * 64 + l16) * 128;
  const int bBase = (wc * 48 + l16) * 128;
  const int xr = l16 & 7;
  const int cph0 = ((lk) ^ xr) * 16;
  const int cph1 = ((4 + lk) ^ xr) * 16;

  f32x4 acc[4][3];
#pragma unroll
  for (int m = 0; m < 4; ++m)
#pragma unroll
    for (int n = 0; n < 3; ++n) acc[m][n] = (f32x4){0.f, 0.f, 0.f, 0.f};

  // prologue: tiles 0 and 1 (sequential; regs reused)
  ISSUE(0, 0);
  WRITEA(0);  // compiler inserts exact vmcnt wait for ar
  ISSUE(1, 1);
  WRITEA(1);
  vmwait<0>();  // B0, B1 landed
  lgwait<0>();  // my ds_writes drained
  BARRIER();

  for (int t = 0; t < nt; ++t) {
    const int b = t & 1;
    const char* pa = smem + b * 16384 + aBase;
    const char* pb = smem + 32768 + b * 12288 + bBase;

    bf16x8 af0[4], af1[4], bf0[3], bf1[3];
#pragma unroll
    for (int m = 0; m < 4; ++m) af0[m] = *(const bf16x8*)(pa + m * 2048 + cph0);
#pragma unroll
    for (int n = 0; n < 3; ++n) bf0[n] = *(const bf16x8*)(pb + n * 2048 + cph0);
#pragma unroll
    for (int m = 0; m < 4; ++m) af1[m] = *(const bf16x8*)(pa + m * 2048 + cph1);
#pragma unroll
    for (int n = 0; n < 3; ++n) bf1[n] = *(const bf16x8*)(pb + n * 2048 + cph1);

    lgwait<7>();  // ks0 ready (7 ks1 reads outstanding)
    __builtin_amdgcn_sched_barrier(0);
    __builtin_amdgcn_s_setprio(1);
#pragma unroll
    for (int m = 0; m < 4; ++m)
#pragma unroll
      for (int n = 0; n < 3; ++n)
        acc[m][n] = __builtin_amdgcn_mfma_f32_16x16x32_bf16(af0[m], bf0[n],
                                                            acc[m][n], 0, 0, 0);
    __builtin_amdgcn_s_setprio(0);
    lgwait<0>();
    __builtin_amdgcn_sched_barrier(0);
    BARRIER();  // buffer b fully read by all waves

    // write A(t+1) into buffer b^1 (loads issued at iter t-1), then free
    // the regs by issuing stage t+2 into buffer b.
    if (t >= 1 && t + 1 < nt) {
      vmwait<3>();  // A(t+1) landed (its 3 B-loads may still be in flight)
      WRITEA(b ^ 1);
    }
    if (t + 2 < nt) ISSUE(t + 2, b);

    __builtin_amdgcn_s_setprio(1);
#pragma unroll
    for (int m = 0; m < 4; ++m)
#pragma unroll
      for (int n = 0; n < 3; ++n)
        acc[m][n] = __builtin_amdgcn_mfma_f32_16x16x32_bf16(af1[m], bf1[n],
                                                            acc[m][n], 0, 0, 0);
    __builtin_amdgcn_s_setprio(0);

    if (t + 1 < nt) {
      if (t + 2 < nt)
        vmwait<11>();  // only stage(t+2)'s 11 remain -> t+1's B landed
      else
        vmwait<0>();
      lgwait<0>();  // drain my ds_writes
      BARRIER();
    }
  }

  // epilogue: +bias only
#pragma unroll
  for (int m = 0; m < 4; ++m) {
#pragma unroll
    for (int n = 0; n < 3; ++n) {
#pragma unroll
      for (int j = 0; j < 4; ++j) {
        const int r = rowBase + wr * 64 + m * 16 + lk * 4 + j;
        const int c = colBase + wc * 48 + n * 16 + l16;
        C[(size_t)r * N + c] = __float2bfloat16(acc[m][n][j] + bias[c]);
      }
    }
  }
}

// ============================== LayerNorm ==================================
template <bool OUTF>
__global__ __launch_bounds__(256) void ln_simple(
    const __hip_bfloat16* __restrict__ Y, __hip_bfloat16* __restrict__ outb,
    float* __restrict__ outf) {
  const int wave = threadIdx.x >> 6, lane = threadIdx.x & 63;
  const size_t base = ((size_t)blockIdx.x * 4 + wave) * 768;

  float v[12];
  float s = 0.f, q = 0.f;
#pragma unroll
  for (int c = 0; c < 3; ++c) {
    const int col = c * 256 + lane * 4;
    ushort4 a = *reinterpret_cast<const ushort4*>(&Y[base + col]);
    float y0 = bf2f(a.x), y1 = bf2f(a.y), y2 = bf2f(a.z), y3 = bf2f(a.w);
    v[c * 4 + 0] = y0; v[c * 4 + 1] = y1; v[c * 4 + 2] = y2; v[c * 4 + 3] = y3;
    s += y0 + y1 + y2 + y3;
    q += y0 * y0 + y1 * y1 + y2 * y2 + y3 * y3;
  }
#pragma unroll
  for (int off = 32; off; off >>= 1) {
    s += __shfl_xor(s, off);
    q += __shfl_xor(q, off);
  }
  const float mu = s * (1.f / 768.f);
  const float rs = rsqrtf(q * (1.f / 768.f) - mu * mu);
#pragma unroll
  for (int c = 0; c < 3; ++c) {
    const int col = c * 256 + lane * 4;
    if (OUTF) {
      float4 o;
      o.x = (v[c * 4 + 0] - mu) * rs;
      o.y = (v[c * 4 + 1] - mu) * rs;
      o.z = (v[c * 4 + 2] - mu) * rs;
      o.w = (v[c * 4 + 3] - mu) * rs;
      *reinterpret_cast<float4*>(&outf[base + col]) = o;
    } else {
      __hip_bfloat16 h0 = __float2bfloat16((v[c * 4 + 0] - mu) * rs);
      __hip_bfloat16 h1 = __float2bfloat16((v[c * 4 + 1] - mu) * rs);
      __hip_bfloat16 h2 = __float2bfloat16((v[c * 4 + 2] - mu) * rs);
      __hip_bfloat16 h3 = __float2bfloat16((v[c * 4 + 3] - mu) * rs);
      ushort4 o;
      o.x = *reinterpret_cast<unsigned short*>(&h0);
      o.y = *reinterpret_cast<unsigned short*>(&h1);
      o.z = *reinterpret_cast<unsigned short*>(&h2);
      o.w = *reinterpret_cast<unsigned short*>(&h3);
      *reinterpret_cast<ushort4*>(&outb[base + col]) = o;
    }
  }
}

// Transpose-cast tile: W (KxN fp32) -> Wt (NxK bf16); addI adds identity.
__device__ inline void tc_tile(const float* __restrict__ W,
                               __hip_bfloat16* __restrict__ Wt, int K, int N,
                               int n0, int k0, int t, bool addI) {
  __shared__ float tile[32][33];
  const int tx = t & 31;
  const int ty = t >> 5;
#pragma unroll
  for (int i = 0; i < 32; i += 8)
    tile[ty + i][tx] = W[(size_t)(k0 + ty + i) * N + n0 + tx];
  __syncthreads();
#pragma unroll
  for (int i = 0; i < 32; i += 8) {
    float v = tile[tx][ty + i];
    if (addI && (n0 + ty + i) == (k0 + tx)) v += 1.0f;
    Wt[(size_t)(n0 + ty + i) * K + k0 + tx] = __float2bfloat16(v);
  }
}

// prep: weight transposes only. Wv^T+I [0,576), W1^T [576,2880),
// W2^T [2880,5184).
__global__ __launch_bounds__(256) void prep_kernel(
    const float* __restrict__ Wv, const float* __restrict__ W1,
    const float* __restrict__ W2, __hip_bfloat16* __restrict__ Wvt,
    __hip_bfloat16* __restrict__ W1t, __hip_bfloat16* __restrict__ W2t) {
  const int bid = blockIdx.x;
  const int t = threadIdx.x;
  if (bid < 576) {
    const int idx = bid;
    tc_tile(Wv, Wvt, 768, 768, (idx % 24) * 32, (idx / 24) * 32, t, true);
  } else if (bid < 2880) {
    const int idx = bid - 576;
    tc_tile(W1, W1t, 768, 3072, (idx % 96) * 32, (idx / 96) * 32, t, false);
  } else {
    const int idx = bid - 2880;
    tc_tile(W2, W2t, 3072, 768, (idx % 24) * 32, (idx / 24) * 32, t, false);
  }
}

extern "C" void kernel_launch(void* const* d_in, const int* in_sizes, int n_in,
                              void* d_out, int out_size, void* d_ws,
                              size_t ws_size, hipStream_t stream) {
  const float* X = (const float*)d_in[0];
  const float* Wv = (const float*)d_in[5];
  const float* bv = (const float*)d_in[6];
  const float* W1 = (const float*)d_in[7];
  const float* b1 = (const float*)d_in[8];
  const float* W2 = (const float*)d_in[9];
  const float* b2 = (const float*)d_in[10];
  float* out = (float*)d_out;

  const int M = 4 * 2048; // 8192 rows
  const int D = 768, H = 3072;

  // workspace layout (round-5/11 proven; Xb slot now unused):
  //  Wvt  @ 12582912  ( 1,179,648)
  //  W1t  @ 13762560  ( 4,718,592)
  //  W2t  @ 18481152  ( 4,718,592)
  //  Yb   @ 23199744  (12,582,912)   (reused as Y2b after LN1)
  //  X1b  @ 35782656  (12,582,912)
  //  Gb   @ 48365568  (50,331,648)
  char* ws = (char*)d_ws;
  __hip_bfloat16* Wvt = (__hip_bfloat16*)(ws + 12582912);
  __hip_bfloat16* W1t = (__hip_bfloat16*)(ws + 13762560);
  __hip_bfloat16* W2t = (__hip_bfloat16*)(ws + 18481152);
  __hip_bfloat16* Yb  = (__hip_bfloat16*)(ws + 23199744);
  __hip_bfloat16* X1b = (__hip_bfloat16*)(ws + 35782656);
  __hip_bfloat16* Gb  = (__hip_bfloat16*)(ws + 48365568);
  __hip_bfloat16* Y2b = Yb;  // Yb dead after LN1

  prep_kernel<<<5184, 256, 0, stream>>>(Wv, W1, W2, Wvt, W1t, W2t);

  // Y = X@(Wv+I) + bv  (fp32 A read directly), grid 64*8 = 512
  gemm1_f32a<<<512, 256, 0, stream>>>(X, Wvt, Yb, bv, M, D, D);
  // X1 = LN(Y)
  ln_simple<false><<<M / 4, 256, 0, stream>>>(Yb, X1b, nullptr);
  // G = relu(X1@W1 + b1), BN=192: grid 64*16 = 1024 (2 exact rounds)
  gemm128<192, 2><<<1024, 256, 0, stream>>>(X1b, W1t, Gb, b1, nullptr, M, H, D);
  // Y2 = G@W2 + b2 + X1 (fused residual), grid 64*8 = 512, nt = 48
  gemm128<96, 3><<<512, 256, 0, stream>>>(Gb, W2t, Y2b, b2, X1b, M, D, H);
  // out = LN(Y2)
  ln_simple<true><<<M / 4, 256, 0, stream>>>(Y2b, nullptr, out);
}

// Round 13
// 120.819 us; speedup vs baseline: 1.0156x; 1.0156x over previous
//
#include <hip/hip_runtime.h>
#include <hip/hip_bf16.h>
#include <math.h>

// ---------------------------------------------------------------------------
// Math note: softmax(A, axis=2) then sum(A, axis=2, keepdims=True) * V == V.
// Pipeline: X1 = LN(X + X@Wv + bv); out = LN(X1 + relu(X1@W1+b1)@W2 + b2)
//
// Round-13 = round-11 verbatim (best measured: 120.9us). Round-12's
// fp32-A GEMM1 reverted (its in-loop vmcnt/lgkm drains cost more than the
// deleted X-cast). GEMM2/GEMM3 are at the 2-barrier structure ceiling
// (~840-900 TF, MfmaUtil ~35%); the 8-phase 256^2 template spills on this
// toolchain (3x identical VGPR-128-cap signature) and is abandoned.
//  - GEMM1 (8192x768x768):  gemm128<96,4>, grid 512, Wv+I folded in prep
//  - GEMM2 (8192x3072x768): gemm128<192,2>, grid 1024 (2 exact rounds)
//  - GEMM3 (8192x768x3072): gemm128<96,3>, grid 512, nt=48
// ---------------------------------------------------------------------------

typedef __bf16 bf16x8 __attribute__((ext_vector_type(8)));
typedef float f32x4 __attribute__((ext_vector_type(4)));

__device__ inline void gload_lds16(const __hip_bfloat16* g, void* lds) {
  __builtin_amdgcn_global_load_lds(
      (const __attribute__((address_space(1))) void*)g,
      (__attribute__((address_space(3))) void*)lds, 16, 0, 0);
}

__device__ inline float bf2f(unsigned short u) {
  union { unsigned int i; float f; } x;
  x.i = ((unsigned int)u) << 16;
  return x.f;
}

#define BARRIER() asm volatile("s_barrier" ::: "memory")

template <int N>
__device__ __forceinline__ void vmwait() {
  if constexpr (N == 0)
    asm volatile("s_waitcnt vmcnt(0)" ::: "memory");
  else if constexpr (N == 7)
    asm volatile("s_waitcnt vmcnt(7)" ::: "memory");
  else if constexpr (N == 8)
    asm volatile("s_waitcnt vmcnt(8)" ::: "memory");
  else if constexpr (N == 10)
    asm volatile("s_waitcnt vmcnt(10)" ::: "memory");
}

template <int N>
__device__ __forceinline__ void lgwait() {
  if constexpr (N == 0)
    asm volatile("s_waitcnt lgkmcnt(0)" ::: "memory");
  else if constexpr (N == 7)
    asm volatile("s_waitcnt lgkmcnt(7)" ::: "memory");
  else if constexpr (N == 8)
    asm volatile("s_waitcnt lgkmcnt(8)" ::: "memory");
  else if constexpr (N == 10)
    asm volatile("s_waitcnt lgkmcnt(10)" ::: "memory");
}

// C(MxN) = A(MxK) @ Bt(NxK)^T, 128 x BNv tile, BK=64, 4 waves (2x2).
// EPI==2: +bias relu; EPI==3: +bias +bf16 residual; EPI==4: +bias only.
template <int BNv, int EPI>
__global__ __launch_bounds__(256, 2) void gemm128(
    const __hip_bfloat16* __restrict__ A, const __hip_bfloat16* __restrict__ Bt,
    __hip_bfloat16* __restrict__ C, const float* __restrict__ bias,
    const __hip_bfloat16* __restrict__ residb, int M, int N, int K) {
  constexpr int NF = BNv / 32;   // n-frags per wave (3, 4, or 6)
  constexpr int BI = BNv / 32;   // B stage instrs per wave
  constexpr int BS = BNv * 128;  // bytes per B buffer
  constexpr int S = 4 + BI;      // stage instrs per wave per K-tile
  // smem: A0[16K] A1[16K] B0[BS] B1[BS]
  __shared__ __align__(16) char smem[32768 + 2 * BS];

  const int bid = blockIdx.x;
  const int mB = M / 128;
  const int rowBase = (bid % mB) * 128;  // row-fastest (L3-friendly)
  const int colBase = (bid / mB) * BNv;
  const int nt = K / 64;

  const int wv = threadIdx.x >> 6;
  const int lane = threadIdx.x & 63;
  const int wr = wv >> 1, wc = wv & 1;   // 2x2 waves
  const int l16 = lane & 15, lk = lane >> 4;

  // staging map (pre-swizzled global source, linear LDS dest; rule 21)
  const int rA = lane >> 3;               // 0..7 row within 8-row stripe
  const int cSw = ((lane & 7) ^ rA) * 8;  // logical col = phys ^ (row&7)
  const __hip_bfloat16* gA = A + (size_t)(rowBase + wv * 32 + rA) * K + cSw;
  const __hip_bfloat16* gB =
      Bt + (size_t)(colBase + wv * 8 * BI + rA) * K + cSw;

  auto STAGE = [&](int kt, int b) {
    const size_t ko = (size_t)kt * 64;
#pragma unroll
    for (int i = 0; i < 4; ++i)
      gload_lds16(gA + (size_t)i * 8 * K + ko,
                  smem + b * 16384 + (wv * 4 + i) * 1024);
#pragma unroll
    for (int i = 0; i < BI; ++i)
      gload_lds16(gB + (size_t)i * 8 * K + ko,
                  smem + 32768 + b * BS + (wv * BI + i) * 1024);
  };

  // ds_read addressing (swizzled chunk: phys = logical ^ (row&7))
  const int aBase = (wr * 64 + l16) * 128;
  const int bBase = (wc * (BNv / 2) + l16) * 128;
  const int xr = l16 & 7;
  const int cph0 = ((lk) ^ xr) * 16;
  const int cph1 = ((4 + lk) ^ xr) * 16;

  f32x4 acc[4][NF];
#pragma unroll
  for (int m = 0; m < 4; ++m)
#pragma unroll
    for (int n = 0; n < NF; ++n) acc[m][n] = (f32x4){0.f, 0.f, 0.f, 0.f};

  STAGE(0, 0);
  if (nt > 1) {
    STAGE(1, 1);
    vmwait<S>();
  } else {
    vmwait<0>();
  }
  BARRIER();

  for (int t = 0; t < nt; ++t) {
    const int b = t & 1;
    const char* pa = smem + b * 16384 + aBase;
    const char* pb = smem + 32768 + b * BS + bBase;

    bf16x8 af0[4], af1[4], bf0[NF], bf1[NF];
#pragma unroll
    for (int m = 0; m < 4; ++m) af0[m] = *(const bf16x8*)(pa + m * 2048 + cph0);
#pragma unroll
    for (int n = 0; n < NF; ++n) bf0[n] = *(const bf16x8*)(pb + n * 2048 + cph0);
#pragma unroll
    for (int m = 0; m < 4; ++m) af1[m] = *(const bf16x8*)(pa + m * 2048 + cph1);
#pragma unroll
    for (int n = 0; n < NF; ++n) bf1[n] = *(const bf16x8*)(pb + n * 2048 + cph1);

    // ks0 frags ready when only the (4+NF) ks1 reads remain (in-order DS)
    lgwait<S>();
    __builtin_amdgcn_sched_barrier(0);
    __builtin_amdgcn_s_setprio(1);
#pragma unroll
    for (int m = 0; m < 4; ++m)
#pragma unroll
      for (int n = 0; n < NF; ++n)
        acc[m][n] = __builtin_amdgcn_mfma_f32_16x16x32_bf16(af0[m], bf0[n],
                                                            acc[m][n], 0, 0, 0);
    __builtin_amdgcn_s_setprio(0);
    lgwait<0>();
    __builtin_amdgcn_sched_barrier(0);
    BARRIER();  // all waves' reads of buffer b complete -> safe to overwrite

    if (t + 2 < nt) STAGE(t + 2, b);  // async issue; overlaps ks1 MFMAs

    __builtin_amdgcn_s_setprio(1);
#pragma unroll
    for (int m = 0; m < 4; ++m)
#pragma unroll
      for (int n = 0; n < NF; ++n)
        acc[m][n] = __builtin_amdgcn_mfma_f32_16x16x32_bf16(af1[m], bf1[n],
                                                            acc[m][n], 0, 0, 0);
    __builtin_amdgcn_s_setprio(0);

    if (t + 1 < nt) {
      if (t + 2 < nt)
        vmwait<S>();  // only the just-issued S remain -> t+1 landed
      else
        vmwait<0>();
      BARRIER();
    }
  }

  // epilogue: C/D layout col=lane&15, row=(lane>>4)*4+reg (verified m89)
#pragma unroll
  for (int m = 0; m < 4; ++m) {
#pragma unroll
    for (int n = 0; n < NF; ++n) {
#pragma unroll
      for (int j = 0; j < 4; ++j) {
        const int r = rowBase + wr * 64 + m * 16 + lk * 4 + j;
        const int c = colBase + wc * (BNv / 2) + n * 16 + l16;
        const size_t idx = (size_t)r * N + c;
        float v = acc[m][n][j] + bias[c];
        if (EPI == 2) v = fmaxf(v, 0.f);
        if (EPI == 3) v += __bfloat162float(residb[idx]);
        C[idx] = __float2bfloat16(v);
      }
    }
  }
}

// LayerNorm over D=768 (biased variance, no eps): one wave per row.
template <bool OUTF>
__global__ __launch_bounds__(256) void ln_simple(
    const __hip_bfloat16* __restrict__ Y, __hip_bfloat16* __restrict__ outb,
    float* __restrict__ outf) {
  const int wave = threadIdx.x >> 6, lane = threadIdx.x & 63;
  const size_t base = ((size_t)blockIdx.x * 4 + wave) * 768;

  float v[12];
  float s = 0.f, q = 0.f;
#pragma unroll
  for (int c = 0; c < 3; ++c) {
    const int col = c * 256 + lane * 4;
    ushort4 a = *reinterpret_cast<const ushort4*>(&Y[base + col]);
    float y0 = bf2f(a.x), y1 = bf2f(a.y), y2 = bf2f(a.z), y3 = bf2f(a.w);
    v[c * 4 + 0] = y0; v[c * 4 + 1] = y1; v[c * 4 + 2] = y2; v[c * 4 + 3] = y3;
    s += y0 + y1 + y2 + y3;
    q += y0 * y0 + y1 * y1 + y2 * y2 + y3 * y3;
  }
#pragma unroll
  for (int off = 32; off; off >>= 1) {
    s += __shfl_xor(s, off);
    q += __shfl_xor(q, off);
  }
  const float mu = s * (1.f / 768.f);
  const float rs = rsqrtf(q * (1.f / 768.f) - mu * mu);
#pragma unroll
  for (int c = 0; c < 3; ++c) {
    const int col = c * 256 + lane * 4;
    if (OUTF) {
      float4 o;
      o.x = (v[c * 4 + 0] - mu) * rs;
      o.y = (v[c * 4 + 1] - mu) * rs;
      o.z = (v[c * 4 + 2] - mu) * rs;
      o.w = (v[c * 4 + 3] - mu) * rs;
      *reinterpret_cast<float4*>(&outf[base + col]) = o;
    } else {
      __hip_bfloat16 h0 = __float2bfloat16((v[c * 4 + 0] - mu) * rs);
      __hip_bfloat16 h1 = __float2bfloat16((v[c * 4 + 1] - mu) * rs);
      __hip_bfloat16 h2 = __float2bfloat16((v[c * 4 + 2] - mu) * rs);
      __hip_bfloat16 h3 = __float2bfloat16((v[c * 4 + 3] - mu) * rs);
      ushort4 o;
      o.x = *reinterpret_cast<unsigned short*>(&h0);
      o.y = *reinterpret_cast<unsigned short*>(&h1);
      o.z = *reinterpret_cast<unsigned short*>(&h2);
      o.w = *reinterpret_cast<unsigned short*>(&h3);
      *reinterpret_cast<ushort4*>(&outb[base + col]) = o;
    }
  }
}

// Transpose-cast tile: W (KxN fp32) -> Wt (NxK bf16); addI adds identity.
__device__ inline void tc_tile(const float* __restrict__ W,
                               __hip_bfloat16* __restrict__ Wt, int K, int N,
                               int n0, int k0, int t, bool addI) {
  __shared__ float tile[32][33];
  const int tx = t & 31;
  const int ty = t >> 5;  // 0..7
#pragma unroll
  for (int i = 0; i < 32; i += 8)
    tile[ty + i][tx] = W[(size_t)(k0 + ty + i) * N + n0 + tx];
  __syncthreads();
#pragma unroll
  for (int i = 0; i < 32; i += 8) {
    float v = tile[tx][ty + i];
    if (addI && (n0 + ty + i) == (k0 + tx)) v += 1.0f;
    Wt[(size_t)(n0 + ty + i) * K + k0 + tx] = __float2bfloat16(v);
  }
}

// Merged preprocessing: X cast [0,6144), Wv^T+I [6144,6720),
// W1^T [6720,9024), W2^T [9024,11328).
__global__ __launch_bounds__(256) void prep_kernel(
    const float* __restrict__ X, const float* __restrict__ Wv,
    const float* __restrict__ W1, const float* __restrict__ W2,
    __hip_bfloat16* __restrict__ Xb, __hip_bfloat16* __restrict__ Wvt,
    __hip_bfloat16* __restrict__ W1t, __hip_bfloat16* __restrict__ W2t) {
  const int bid = blockIdx.x;
  const int t = threadIdx.x;
  if (bid < 6144) {  // cast 8192*768 fp32 -> bf16, 4/thread
    const int i = bid * 256 + t;
    float4 v = reinterpret_cast<const float4*>(X)[i];
    __hip_bfloat16 h0 = __float2bfloat16(v.x), h1 = __float2bfloat16(v.y);
    __hip_bfloat16 h2 = __float2bfloat16(v.z), h3 = __float2bfloat16(v.w);
    ushort4 o;
    o.x = *reinterpret_cast<unsigned short*>(&h0);
    o.y = *reinterpret_cast<unsigned short*>(&h1);
    o.z = *reinterpret_cast<unsigned short*>(&h2);
    o.w = *reinterpret_cast<unsigned short*>(&h3);
    reinterpret_cast<ushort4*>(Xb)[i] = o;
  } else if (bid < 6720) {  // Wv (768x768), +I folded
    const int idx = bid - 6144;
    tc_tile(Wv, Wvt, 768, 768, (idx % 24) * 32, (idx / 24) * 32, t, true);
  } else if (bid < 9024) {  // W1 (768x3072) -> W1t (3072x768)
    const int idx = bid - 6720;
    tc_tile(W1, W1t, 768, 3072, (idx % 96) * 32, (idx / 96) * 32, t, false);
  } else {  // W2 (3072x768) -> W2t (768x3072)
    const int idx = bid - 9024;
    tc_tile(W2, W2t, 3072, 768, (idx % 24) * 32, (idx / 24) * 32, t, false);
  }
}

extern "C" void kernel_launch(void* const* d_in, const int* in_sizes, int n_in,
                              void* d_out, int out_size, void* d_ws,
                              size_t ws_size, hipStream_t stream) {
  const float* X = (const float*)d_in[0];
  const float* Wv = (const float*)d_in[5];
  const float* bv = (const float*)d_in[6];
  const float* W1 = (const float*)d_in[7];
  const float* b1 = (const float*)d_in[8];
  const float* W2 = (const float*)d_in[9];
  const float* b2 = (const float*)d_in[10];
  float* out = (float*)d_out;

  const int M = 4 * 2048; // 8192 rows
  const int D = 768, H = 3072;

  // workspace layout (round-5 proven), total 98,697,216:
  //  Xb   @ 0         (12,582,912)
  //  Wvt  @ 12582912  ( 1,179,648)
  //  W1t  @ 13762560  ( 4,718,592)
  //  W2t  @ 18481152  ( 4,718,592)
  //  Yb   @ 23199744  (12,582,912)   (reused as Y2b after LN1)
  //  X1b  @ 35782656  (12,582,912)
  //  Gb   @ 48365568  (50,331,648)
  char* ws = (char*)d_ws;
  __hip_bfloat16* Xb  = (__hip_bfloat16*)(ws);
  __hip_bfloat16* Wvt = (__hip_bfloat16*)(ws + 12582912);
  __hip_bfloat16* W1t = (__hip_bfloat16*)(ws + 13762560);
  __hip_bfloat16* W2t = (__hip_bfloat16*)(ws + 18481152);
  __hip_bfloat16* Yb  = (__hip_bfloat16*)(ws + 23199744);
  __hip_bfloat16* X1b = (__hip_bfloat16*)(ws + 35782656);
  __hip_bfloat16* Gb  = (__hip_bfloat16*)(ws + 48365568);
  __hip_bfloat16* Y2b = Yb;  // Yb dead after LN1

  prep_kernel<<<11328, 256, 0, stream>>>(X, Wv, W1, W2, Xb, Wvt, W1t, W2t);

  // Y = X@(Wv+I) + bv  (residual folded into weight), grid 64*8 = 512
  gemm128<96, 4><<<512, 256, 0, stream>>>(Xb, Wvt, Yb, bv, nullptr, M, D, D);
  // X1 = LN(Y)
  ln_simple<false><<<M / 4, 256, 0, stream>>>(Yb, X1b, nullptr);
  // G = relu(X1@W1 + b1), BN=192: grid 64*16 = 1024 (2 exact rounds)
  gemm128<192, 2><<<1024, 256, 0, stream>>>(X1b, W1t, Gb, b1, nullptr, M, H, D);
  // Y2 = G@W2 + b2 + X1 (fused residual), grid 64*8 = 512, nt = 48
  gemm128<96, 3><<<512, 256, 0, stream>>>(Gb, W2t, Y2b, b2, X1b, M, D, H);
  // out = LN(Y2)
  ln_simple<true><<<M / 4, 256, 0, stream>>>(Y2b, nullptr, out);
}